// Round 1
// baseline (1068.609 us; speedup 1.0000x reference)
//
#include <hip/hip_runtime.h>
#include <hip/hip_bf16.h>
#include <cstdint>

#define BT 4096
#define H  2048
#define V  32000
#define TM 128
#define TN 128
#define BK 32
#define NVT (V/TN)   // 250 V-tiles
#define NRT (BT/TM)  // 32 row-tiles

typedef __bf16 bf16x8 __attribute__((ext_vector_type(8)));
typedef float  f32x4  __attribute__((ext_vector_type(4)));

__device__ __forceinline__ void async_load16(const void* g, void* l) {
    __builtin_amdgcn_global_load_lds(
        (__attribute__((address_space(1))) uint32_t*)(void*)g,
        (__attribute__((address_space(3))) uint32_t*)l, 16, 0, 0);
}

// ---------------- cast fp32 -> bf16, vectorized ----------------
__global__ void cast_f32_bf16(const float4* __restrict__ in,
                              ushort4* __restrict__ out, int n4) {
    int i = blockIdx.x * blockDim.x + threadIdx.x;
    if (i < n4) {
        float4 v = in[i];
        union { __hip_bfloat16 h[4]; ushort4 u; } p;
        p.h[0] = __float2bfloat16(v.x);
        p.h[1] = __float2bfloat16(v.y);
        p.h[2] = __float2bfloat16(v.z);
        p.h[3] = __float2bfloat16(v.w);
        out[i] = p.u;
    }
}

// ---------------- fused GEMM tile + online LSE partials ----------------
// C[t,v] = sum_h x[t,h]*w[v,h] + bias[v]; per 128x128 tile emit per-row
// (max, sumexp) partials and the target logit if it lands in this tile.
__global__ __launch_bounds__(256) void gemm_lse(
    const __hip_bfloat16* __restrict__ Xb,   // [BT,H] bf16
    const __hip_bfloat16* __restrict__ Wb,   // [V,H]  bf16
    const float* __restrict__ bias,          // [V]
    const int*  __restrict__ target,         // [BT]
    float* __restrict__ part_m,              // [NVT][BT]
    float* __restrict__ part_l,              // [NVT][BT]
    float* __restrict__ tgt_logit)           // [BT]
{
    __shared__ __align__(16) __hip_bfloat16 As[TM * BK];
    __shared__ __align__(16) __hip_bfloat16 Bs[TN * BK];
    __shared__ float red_m[2][TM];
    __shared__ float red_l[2][TM];
    __shared__ int   tgts[TM];

    const int tid  = threadIdx.x;
    const int lane = tid & 63;
    const int wave = tid >> 6;
    const int wm   = wave >> 1;      // 0..1 : 64-row half
    const int wn   = wave & 1;       // 0..1 : 64-col half
    const int row0 = blockIdx.x * TM;
    const int col0 = blockIdx.y * TN;

    if (tid < TM) tgts[tid] = target[row0 + tid];

    f32x4 acc[4][4];
#pragma unroll
    for (int i = 0; i < 4; i++)
#pragma unroll
        for (int j = 0; j < 4; j++) acc[i][j] = (f32x4){0.f, 0.f, 0.f, 0.f};

    const int srow = lane >> 2;        // 0..15 row within 16-row load group
    const int skb  = (lane & 3) * 8;   // bf16 offset within BK (4x16B per row)

    const __hip_bfloat16* Abase = Xb + (size_t)row0 * H;
    const __hip_bfloat16* Bbase = Wb + (size_t)col0 * H;

    for (int k0 = 0; k0 < H; k0 += BK) {
        // stage A,B tiles: each wave covers 16 rows per load, lane->LDS base+lane*16
#pragma unroll
        for (int L = 0; L < 2; L++) {
            const int rb = wave * 16 + L * 64;
            async_load16(Abase + (size_t)(rb + srow) * H + k0 + skb, &As[rb * BK]);
            async_load16(Bbase + (size_t)(rb + srow) * H + k0 + skb, &Bs[rb * BK]);
        }
        __syncthreads();   // compiler inserts vmcnt(0) drain before barrier

        const int q8 = (lane >> 4) * 8;   // k-offset of this quad
        const int lr = lane & 15;         // row/col within 16
        bf16x8 af[4], bf[4];
#pragma unroll
        for (int i = 0; i < 4; i++)
            af[i] = *(const bf16x8*)&As[(wm * 64 + i * 16 + lr) * BK + q8];
#pragma unroll
        for (int j = 0; j < 4; j++)
            bf[j] = *(const bf16x8*)&Bs[(wn * 64 + j * 16 + lr) * BK + q8];
#pragma unroll
        for (int i = 0; i < 4; i++)
#pragma unroll
            for (int j = 0; j < 4; j++)
                acc[i][j] = __builtin_amdgcn_mfma_f32_16x16x32_bf16(
                    af[i], bf[j], acc[i][j], 0, 0, 0);
        __syncthreads();
    }

    // ---- epilogue: bias add, target grab, per-row max/sumexp over 64 cols ----
    const int lr   = lane & 15;
    const int quad = lane >> 4;
    float bj[4];
#pragma unroll
    for (int j = 0; j < 4; j++) bj[j] = bias[col0 + wn * 64 + j * 16 + lr];

#pragma unroll
    for (int i = 0; i < 4; i++) {
#pragma unroll
        for (int r = 0; r < 4; r++) {
            const int rit = wm * 64 + i * 16 + quad * 4 + r;  // C/D: row=quad*4+reg
            float v[4];
#pragma unroll
            for (int j = 0; j < 4; j++) v[j] = acc[i][j][r] + bj[j];
            const int tg = tgts[rit];
#pragma unroll
            for (int j = 0; j < 4; j++)
                if (col0 + wn * 64 + j * 16 + lr == tg)
                    tgt_logit[row0 + rit] = v[j];  // exactly one writer globally
            float mx = fmaxf(fmaxf(v[0], v[1]), fmaxf(v[2], v[3]));
            float se = __expf(v[0] - mx) + __expf(v[1] - mx) +
                       __expf(v[2] - mx) + __expf(v[3] - mx);
            // reduce across the 16 lanes of this quad (same row)
#pragma unroll
            for (int d = 1; d < 16; d <<= 1) {
                float om = __shfl_xor(mx, d);
                float os = __shfl_xor(se, d);
                float nm = fmaxf(mx, om);
                se = se * __expf(mx - nm) + os * __expf(om - nm);
                mx = nm;
            }
            if (lr == 0) { red_m[wn][rit] = mx; red_l[wn][rit] = se; }
        }
    }
    __syncthreads();
    if (tid < TM) {
        float m0 = red_m[0][tid], m1 = red_m[1][tid];
        float l0 = red_l[0][tid], l1 = red_l[1][tid];
        float M = fmaxf(m0, m1);
        float L = l0 * __expf(m0 - M) + l1 * __expf(m1 - M);
        part_m[(size_t)blockIdx.y * BT + row0 + tid] = M;
        part_l[(size_t)blockIdx.y * BT + row0 + tid] = L;
    }
}

// ---------------- merge partials -> per-token NLL -> sum ----------------
__global__ void finalize(const float* __restrict__ part_m,
                         const float* __restrict__ part_l,
                         const float* __restrict__ tgt_logit,
                         const int*  __restrict__ target,
                         float* __restrict__ accum)  // accum[0]=sum, accum[1]=count
{
    const int t = blockIdx.x * blockDim.x + threadIdx.x;  // exact: BT threads
    float M = -1e30f;
    for (int j = 0; j < NVT; j++) M = fmaxf(M, part_m[(size_t)j * BT + t]);
    float L = 0.f;
    for (int j = 0; j < NVT; j++)
        L += part_l[(size_t)j * BT + t] * __expf(part_m[(size_t)j * BT + t] - M);
    float loss = 0.f, cnt = 0.f;
    const int tg = target[t];
    if (tg != -100) {
        loss = (M + __logf(L)) - tgt_logit[t];
        cnt  = 1.f;
    }
#pragma unroll
    for (int d = 32; d; d >>= 1) {
        loss += __shfl_down(loss, d);
        cnt  += __shfl_down(cnt, d);
    }
    __shared__ float sm[4], sc[4];
    const int wv = threadIdx.x >> 6, ln = threadIdx.x & 63;
    if (ln == 0) { sm[wv] = loss; sc[wv] = cnt; }
    __syncthreads();
    if (threadIdx.x == 0) {
        float Ls = 0.f, Cs = 0.f;
        for (int w = 0; w < 4; w++) { Ls += sm[w]; Cs += sc[w]; }
        atomicAdd(&accum[0], Ls);
        atomicAdd(&accum[1], Cs);
    }
}

__global__ void final_div(const float* __restrict__ accum, float* __restrict__ out) {
    out[0] = accum[0] / fmaxf(accum[1], 1.f);
}

extern "C" void kernel_launch(void* const* d_in, const int* in_sizes, int n_in,
                              void* d_out, int out_size, void* d_ws, size_t ws_size,
                              hipStream_t stream) {
    const float* x      = (const float*)d_in[0];
    const int*   target = (const int*)d_in[1];
    const float* w      = (const float*)d_in[2];
    const float* bias   = (const float*)d_in[3];

    char* ws = (char*)d_ws;
    size_t off = 0;
    auto alloc = [&](size_t bytes) {
        void* p = ws + off;
        off += (bytes + 255) & ~(size_t)255;
        return p;
    };
    __hip_bfloat16* Xb     = (__hip_bfloat16*)alloc((size_t)BT * H * 2);
    __hip_bfloat16* Wb     = (__hip_bfloat16*)alloc((size_t)V * H * 2);
    float* part_m          = (float*)alloc((size_t)NVT * BT * 4);
    float* part_l          = (float*)alloc((size_t)NVT * BT * 4);
    float* tgtl            = (float*)alloc((size_t)BT * 4);
    float* accum           = (float*)alloc(256);

    const int n1 = BT * H / 4;
    cast_f32_bf16<<<(n1 + 255) / 256, 256, 0, stream>>>((const float4*)x, (ushort4*)Xb, n1);
    const int n2 = V * H / 4;
    cast_f32_bf16<<<(n2 + 255) / 256, 256, 0, stream>>>((const float4*)w, (ushort4*)Wb, n2);
    hipMemsetAsync(accum, 0, 8, stream);

    dim3 grid(NRT, NVT);  // x=row-tiles fastest: concurrent blocks share V-tiles (W L2 reuse)
    gemm_lse<<<grid, 256, 0, stream>>>(Xb, Wb, bias, target, part_m, part_l, tgtl);

    finalize<<<BT / 256, 256, 0, stream>>>(part_m, part_l, tgtl, target, accum);
    final_div<<<1, 1, 0, stream>>>(accum, (float*)d_out);
}

// Round 2
// 830.055 us; speedup vs baseline: 1.2874x; 1.2874x over previous
//
#include <hip/hip_runtime.h>
#include <hip/hip_bf16.h>
#include <cstdint>

#define BT 4096
#define H  2048
#define V  32000
#define TM 128
#define TN 128
#define BK 128          // fp8 bytes == elements
#define NVT (V/TN)      // 250
#define NRT (BT/TM)     // 32
#define WSCALE 64.0f
#define INV_WSCALE 0.015625f

typedef int   v8i   __attribute__((ext_vector_type(8)));
typedef float f32x4 __attribute__((ext_vector_type(4)));

__device__ __forceinline__ void async_load16(const void* g, void* l) {
    __builtin_amdgcn_global_load_lds(
        (__attribute__((address_space(1))) uint32_t*)(void*)g,
        (__attribute__((address_space(3))) uint32_t*)l, 16, 0, 0);
}

// ---------------- quantize fp32 -> fp8 e4m3 (OCP), 8 elems/thread ----------
__global__ void quant_fp8(const float4* __restrict__ in, int2* __restrict__ out,
                          int n8, float scale, float* accum_zero) {
    int i = blockIdx.x * blockDim.x + threadIdx.x;
    if (accum_zero != nullptr && i == 0) { accum_zero[0] = 0.f; accum_zero[1] = 0.f; }
    if (i < n8) {
        float4 a = in[2 * i];
        float4 b = in[2 * i + 1];
        int lo = __builtin_amdgcn_cvt_pk_fp8_f32(a.x * scale, a.y * scale, 0, false);
        lo     = __builtin_amdgcn_cvt_pk_fp8_f32(a.z * scale, a.w * scale, lo, true);
        int hi = __builtin_amdgcn_cvt_pk_fp8_f32(b.x * scale, b.y * scale, 0, false);
        hi     = __builtin_amdgcn_cvt_pk_fp8_f32(b.z * scale, b.w * scale, hi, true);
        out[i] = make_int2(lo, hi);
    }
}

// ---------------- fused fp8 GEMM tile + online LSE partials ----------------
// logits[t,v] = (sum_h xq[t,h]*(64*w)q[v,h]) / 64 + bias[v]
// MX-scaled MFMA with all-ones E8M0 scales == pure fp8 GEMM at 2x bf16 rate.
__global__ __launch_bounds__(256) void gemm_lse(
    const uint8_t* __restrict__ Xq,          // [BT,H] fp8
    const uint8_t* __restrict__ Wq,          // [V,H]  fp8 (pre-scaled x64)
    const float* __restrict__ bias,          // [V]
    const int*  __restrict__ target,         // [BT]
    float* __restrict__ part_m,              // [NVT][BT]
    float* __restrict__ part_l,              // [NVT][BT]
    float* __restrict__ tgt_logit)           // [BT]
{
    // XOR-swizzled tiles: physical 16B chunk c of row r holds logical chunk
    // c ^ (r&7).  Swizzle applied on the GLOBAL address side (global_load_lds
    // writes wave-uniform-base + lane*16, so LDS side is fixed).
    __shared__ __align__(16) uint8_t As[TM * BK];
    __shared__ __align__(16) uint8_t Bs[TN * BK];
    __shared__ float red_m[2][TM];
    __shared__ float red_l[2][TM];
    __shared__ int   tgts[TM];

    const int tid  = threadIdx.x;
    const int lane = tid & 63;
    const int wave = tid >> 6;
    const int wm   = wave >> 1;      // 64-row half
    const int wn   = wave & 1;       // 64-col half
    const int row0 = blockIdx.x * TM;
    const int col0 = blockIdx.y * TN;

    if (tid < TM) tgts[tid] = target[row0 + tid];

    f32x4 acc[4][4];
#pragma unroll
    for (int i = 0; i < 4; i++)
#pragma unroll
        for (int j = 0; j < 4; j++) acc[i][j] = (f32x4){0.f, 0.f, 0.f, 0.f};

    // staging: each wave-issue covers 8 rows x 128B; lane l -> row 8g+l/8,
    // physical chunk l%8; fetch logical chunk (l%8)^(row&7) = (l%8)^(l/8)
    const int srow   = lane >> 3;                    // 0..7
    const int schunk = ((lane & 7) ^ srow) * 16;     // swizzled byte offset

    const uint8_t* Abase = Xq + (size_t)row0 * H;
    const uint8_t* Bbase = Wq + (size_t)col0 * H;

    const int lr  = lane & 15;
    const int g32 = lane >> 4;       // k-group: logical chunks {2g,2g+1}

    for (int k0 = 0; k0 < H; k0 += BK) {
#pragma unroll
        for (int L = 0; L < 4; L++) {
            const int g = wave * 4 + L;              // 0..15 -> rows 8g..8g+7
            async_load16(Abase + (size_t)(8 * g + srow) * H + k0 + schunk, &As[g * 1024]);
            async_load16(Bbase + (size_t)(8 * g + srow) * H + k0 + schunk, &Bs[g * 1024]);
        }
        __syncthreads();

        union Frag { int4 q[2]; v8i v; };
        Frag af[4], bf[4];
#pragma unroll
        for (int i = 0; i < 4; i++) {
            const int r  = wm * 64 + i * 16 + lr;
            const int p0 = (2 * g32) ^ (r & 7);
            const int4* base = (const int4*)&As[r * BK];
            af[i].q[0] = base[p0];
            af[i].q[1] = base[p0 ^ 1];
        }
#pragma unroll
        for (int j = 0; j < 4; j++) {
            const int r  = wn * 64 + j * 16 + lr;
            const int p0 = (2 * g32) ^ (r & 7);
            const int4* base = (const int4*)&Bs[r * BK];
            bf[j].q[0] = base[p0];
            bf[j].q[1] = base[p0 ^ 1];
        }
#pragma unroll
        for (int i = 0; i < 4; i++)
#pragma unroll
            for (int j = 0; j < 4; j++)
                acc[i][j] = __builtin_amdgcn_mfma_scale_f32_16x16x128_f8f6f4(
                    af[i].v, bf[j].v, acc[i][j],
                    0 /*A=e4m3*/, 0 /*B=e4m3*/,
                    0, 0x7f7f7f7f, 0, 0x7f7f7f7f);   // all scales = 2^0
        __syncthreads();
    }

    // ---- epilogue: unscale, bias add, target grab, per-row max/sumexp ----
    const int quad = lane >> 4;
    float bj[4];
#pragma unroll
    for (int j = 0; j < 4; j++) bj[j] = bias[col0 + wn * 64 + j * 16 + lr];

#pragma unroll
    for (int i = 0; i < 4; i++) {
#pragma unroll
        for (int r = 0; r < 4; r++) {
            const int rit = wm * 64 + i * 16 + quad * 4 + r;  // C/D: row=quad*4+reg
            float v[4];
#pragma unroll
            for (int j = 0; j < 4; j++) v[j] = acc[i][j][r] * INV_WSCALE + bj[j];
            const int tg = tgts[rit];
#pragma unroll
            for (int j = 0; j < 4; j++)
                if (col0 + wn * 64 + j * 16 + lr == tg)
                    tgt_logit[row0 + rit] = v[j];  // exactly one writer globally
            float mx = fmaxf(fmaxf(v[0], v[1]), fmaxf(v[2], v[3]));
            float se = __expf(v[0] - mx) + __expf(v[1] - mx) +
                       __expf(v[2] - mx) + __expf(v[3] - mx);
#pragma unroll
            for (int d = 1; d < 16; d <<= 1) {
                float om = __shfl_xor(mx, d);
                float os = __shfl_xor(se, d);
                float nm = fmaxf(mx, om);
                se = se * __expf(mx - nm) + os * __expf(om - nm);
                mx = nm;
            }
            if (lr == 0) { red_m[wn][rit] = mx; red_l[wn][rit] = se; }
        }
    }
    __syncthreads();
    if (tid < TM) {
        float m0 = red_m[0][tid], m1 = red_m[1][tid];
        float l0 = red_l[0][tid], l1 = red_l[1][tid];
        float M = fmaxf(m0, m1);
        float L = l0 * __expf(m0 - M) + l1 * __expf(m1 - M);
        part_m[(size_t)blockIdx.y * BT + row0 + tid] = M;
        part_l[(size_t)blockIdx.y * BT + row0 + tid] = L;
    }
}

// ---------------- merge partials -> per-token NLL -> sum ----------------
__global__ void finalize(const float* __restrict__ part_m,
                         const float* __restrict__ part_l,
                         const float* __restrict__ tgt_logit,
                         const int*  __restrict__ target,
                         float* __restrict__ accum)  // accum[0]=sum, accum[1]=count
{
    const int t = blockIdx.x * blockDim.x + threadIdx.x;  // exact: BT threads
    float M = -1e30f;
    for (int j = 0; j < NVT; j++) M = fmaxf(M, part_m[(size_t)j * BT + t]);
    float L = 0.f;
    for (int j = 0; j < NVT; j++)
        L += part_l[(size_t)j * BT + t] * __expf(part_m[(size_t)j * BT + t] - M);
    float loss = 0.f, cnt = 0.f;
    const int tg = target[t];
    if (tg != -100) {
        loss = (M + __logf(L)) - tgt_logit[t];
        cnt  = 1.f;
    }
#pragma unroll
    for (int d = 32; d; d >>= 1) {
        loss += __shfl_down(loss, d);
        cnt  += __shfl_down(cnt, d);
    }
    __shared__ float sm[4], sc[4];
    const int wv = threadIdx.x >> 6, ln = threadIdx.x & 63;
    if (ln == 0) { sm[wv] = loss; sc[wv] = cnt; }
    __syncthreads();
    if (threadIdx.x == 0) {
        float Ls = 0.f, Cs = 0.f;
        for (int w = 0; w < 4; w++) { Ls += sm[w]; Cs += sc[w]; }
        atomicAdd(&accum[0], Ls);
        atomicAdd(&accum[1], Cs);
    }
}

__global__ void final_div(const float* __restrict__ accum, float* __restrict__ out) {
    out[0] = accum[0] / fmaxf(accum[1], 1.f);
}

extern "C" void kernel_launch(void* const* d_in, const int* in_sizes, int n_in,
                              void* d_out, int out_size, void* d_ws, size_t ws_size,
                              hipStream_t stream) {
    const float* x      = (const float*)d_in[0];
    const int*   target = (const int*)d_in[1];
    const float* w      = (const float*)d_in[2];
    const float* bias   = (const float*)d_in[3];

    char* ws = (char*)d_ws;
    size_t off = 0;
    auto alloc = [&](size_t bytes) {
        void* p = ws + off;
        off += (bytes + 255) & ~(size_t)255;
        return p;
    };
    uint8_t* Xq   = (uint8_t*)alloc((size_t)BT * H);
    uint8_t* Wq   = (uint8_t*)alloc((size_t)V * H);
    float* part_m = (float*)alloc((size_t)NVT * BT * 4);
    float* part_l = (float*)alloc((size_t)NVT * BT * 4);
    float* tgtl   = (float*)alloc((size_t)BT * 4);
    float* accum  = (float*)alloc(256);

    const int n1 = BT * H / 8;
    quant_fp8<<<(n1 + 255) / 256, 256, 0, stream>>>(
        (const float4*)x, (int2*)Xq, n1, 1.0f, accum);   // also zeroes accum
    const int n2 = V * H / 8;
    quant_fp8<<<(n2 + 255) / 256, 256, 0, stream>>>(
        (const float4*)w, (int2*)Wq, n2, WSCALE, nullptr);

    dim3 grid(NRT, NVT);  // x fastest: consecutive blocks share the same W-tile (L2 reuse)
    gemm_lse<<<grid, 256, 0, stream>>>(Xq, Wq, bias, target, part_m, part_l, tgtl);

    finalize<<<BT / 256, 256, 0, stream>>>(part_m, part_l, tgtl, target, accum);
    final_div<<<1, 1, 0, stream>>>(accum, (float*)d_out);
}

// Round 3
// 801.231 us; speedup vs baseline: 1.3337x; 1.0360x over previous
//
#include <hip/hip_runtime.h>
#include <hip/hip_bf16.h>
#include <cstdint>

#define BT 4096
#define H  2048
#define V  32000
#define TM 128
#define TN 128
#define BK 128          // fp8 bytes == elements
#define NVT (V/TN)      // 250
#define NRT (BT/TM)     // 32
#define PJ  256         // padded partials row stride (floats)
#define WSCALE 64.0f
#define INV_WSCALE 0.015625f

typedef int   v8i   __attribute__((ext_vector_type(8)));
typedef float f32x4 __attribute__((ext_vector_type(4)));

__device__ __forceinline__ void async_load16(const void* g, void* l) {
    __builtin_amdgcn_global_load_lds(
        (__attribute__((address_space(1))) uint32_t*)(void*)g,
        (__attribute__((address_space(3))) uint32_t*)l, 16, 0, 0);
}

// ------- quantize X and W fp32 -> fp8 e4m3 in ONE kernel, 16B/lane loads ----
__global__ void quant_all(const float4* __restrict__ X4, const float4* __restrict__ W4,
                          int* __restrict__ Xq, int* __restrict__ Wq,
                          float* __restrict__ accum) {
    const int NX = BT * H / 4;
    const int NW = (int)((size_t)V * H / 4);
    int i = blockIdx.x * blockDim.x + threadIdx.x;
    if (i == 0) { accum[0] = 0.f; accum[1] = 0.f; }
    if (i < NX) {
        float4 v = X4[i];
        int p = __builtin_amdgcn_cvt_pk_fp8_f32(v.x, v.y, 0, false);
        p     = __builtin_amdgcn_cvt_pk_fp8_f32(v.z, v.w, p, true);
        Xq[i] = p;
    } else if (i < NX + NW) {
        int j = i - NX;
        float4 v = W4[j];
        int p = __builtin_amdgcn_cvt_pk_fp8_f32(v.x * WSCALE, v.y * WSCALE, 0, false);
        p     = __builtin_amdgcn_cvt_pk_fp8_f32(v.z * WSCALE, v.w * WSCALE, p, true);
        Wq[j] = p;
    }
}

// ---------------- fused fp8 GEMM tile + online LSE partials ----------------
// logits[t,v] = (sum_h xq[t,h]*(64*w)q[v,h]) / 64 + bias[v]
// MX-scaled MFMA with all-ones E8M0 scales == pure fp8 GEMM at 2x bf16 rate.
__global__ __launch_bounds__(256) void gemm_lse(
    const uint8_t* __restrict__ Xq,          // [BT,H] fp8
    const uint8_t* __restrict__ Wq,          // [V,H]  fp8 (pre-scaled x64)
    const float* __restrict__ bias,          // [V]
    const int*  __restrict__ target,         // [BT]
    float* __restrict__ part_m,              // [BT][PJ]
    float* __restrict__ part_l,              // [BT][PJ]
    float* __restrict__ tgt_logit)           // [BT]
{
    // XOR-swizzled tiles: physical 16B chunk c of row r holds logical chunk
    // c ^ (r&7) (swizzle on the GLOBAL side; global_load_lds LDS side is fixed).
    __shared__ __align__(16) uint8_t As[TM * BK];
    __shared__ __align__(16) uint8_t Bs[TN * BK];
    __shared__ float red_m[2][TM];
    __shared__ float red_l[2][TM];
    __shared__ int   tgts[TM];

    const int tid  = threadIdx.x;
    const int lane = tid & 63;
    const int wave = tid >> 6;
    const int wm   = wave >> 1;      // 64-row half
    const int wn   = wave & 1;       // 64-col half
    const int row0 = blockIdx.x * TM;
    const int col0 = blockIdx.y * TN;

    if (tid < TM) tgts[tid] = target[row0 + tid];

    f32x4 acc[4][4];
#pragma unroll
    for (int i = 0; i < 4; i++)
#pragma unroll
        for (int j = 0; j < 4; j++) acc[i][j] = (f32x4){0.f, 0.f, 0.f, 0.f};

    // staging: lane l -> row 8g+l/8, physical chunk l%8 holds logical (l%8)^(l/8)
    const int srow   = lane >> 3;                    // 0..7
    const int schunk = ((lane & 7) ^ srow) * 16;     // swizzled byte offset

    const uint8_t* Abase = Xq + (size_t)row0 * H;
    const uint8_t* Bbase = Wq + (size_t)col0 * H;

    const int lr  = lane & 15;
    const int g32 = lane >> 4;       // k-group: logical chunks {2g,2g+1}

    for (int k0 = 0; k0 < H; k0 += BK) {
#pragma unroll
        for (int L = 0; L < 4; L++) {
            const int g = wave * 4 + L;              // rows 8g..8g+7
            async_load16(Abase + (size_t)(8 * g + srow) * H + k0 + schunk, &As[g * 1024]);
            async_load16(Bbase + (size_t)(8 * g + srow) * H + k0 + schunk, &Bs[g * 1024]);
        }
        __syncthreads();

        union Frag { int4 q[2]; v8i v; };
        Frag af[4], bf[4];
#pragma unroll
        for (int i = 0; i < 4; i++) {
            const int r  = wm * 64 + i * 16 + lr;
            const int p0 = (2 * g32) ^ (r & 7);
            const int4* base = (const int4*)&As[r * BK];
            af[i].q[0] = base[p0];
            af[i].q[1] = base[p0 ^ 1];
        }
#pragma unroll
        for (int j = 0; j < 4; j++) {
            const int r  = wn * 64 + j * 16 + lr;
            const int p0 = (2 * g32) ^ (r & 7);
            const int4* base = (const int4*)&Bs[r * BK];
            bf[j].q[0] = base[p0];
            bf[j].q[1] = base[p0 ^ 1];
        }
#pragma unroll
        for (int i = 0; i < 4; i++)
#pragma unroll
            for (int j = 0; j < 4; j++)
                acc[i][j] = __builtin_amdgcn_mfma_scale_f32_16x16x128_f8f6f4(
                    af[i].v, bf[j].v, acc[i][j],
                    0 /*A=e4m3*/, 0 /*B=e4m3*/,
                    0, 0x7f7f7f7f, 0, 0x7f7f7f7f);   // all scales = 2^0
        __syncthreads();
    }

    // ---- epilogue: unscale, bias, target grab, max-first reduce, ONE exp pass
    const int quad = lane >> 4;
    float bj[4];
#pragma unroll
    for (int j = 0; j < 4; j++) bj[j] = bias[col0 + wn * 64 + j * 16 + lr];

#pragma unroll
    for (int i = 0; i < 4; i++) {
#pragma unroll
        for (int r = 0; r < 4; r++) {
            const int rit = wm * 64 + i * 16 + quad * 4 + r;  // C/D: row=quad*4+reg
            float v[4];
#pragma unroll
            for (int j = 0; j < 4; j++) v[j] = acc[i][j][r] * INV_WSCALE + bj[j];
            const int tg = tgts[rit];
#pragma unroll
            for (int j = 0; j < 4; j++)
                if (col0 + wn * 64 + j * 16 + lr == tg)
                    tgt_logit[row0 + rit] = v[j];  // exactly one writer globally
            // max over this row's 64 cols (4 regs x 16 lanes), cheap fmax shuffles
            float mx = fmaxf(fmaxf(v[0], v[1]), fmaxf(v[2], v[3]));
#pragma unroll
            for (int d = 1; d < 16; d <<= 1) mx = fmaxf(mx, __shfl_xor(mx, d));
            // single exp pass, then sum shuffles
            float se = __expf(v[0] - mx) + __expf(v[1] - mx) +
                       __expf(v[2] - mx) + __expf(v[3] - mx);
#pragma unroll
            for (int d = 1; d < 16; d <<= 1) se += __shfl_xor(se, d);
            if (lr == 0) { red_m[wn][rit] = mx; red_l[wn][rit] = se; }
        }
    }
    __syncthreads();
    if (tid < TM) {
        float m0 = red_m[0][tid], m1 = red_m[1][tid];
        float l0 = red_l[0][tid], l1 = red_l[1][tid];
        float M = fmaxf(m0, m1);
        float L = l0 * __expf(m0 - M) + l1 * __expf(m1 - M);
        // transposed layout: one contiguous row of 250 partials per token
        part_m[(size_t)(row0 + tid) * PJ + blockIdx.y] = M;
        part_l[(size_t)(row0 + tid) * PJ + blockIdx.y] = L;
    }
}

// ------- merge partials: one WAVE per token, lane-parallel over V-tiles -----
__global__ void finalize(const float* __restrict__ part_m,
                         const float* __restrict__ part_l,
                         const float* __restrict__ tgt_logit,
                         const int*  __restrict__ target,
                         float* __restrict__ accum)  // accum[0]=sum, accum[1]=count
{
    const int wave = threadIdx.x >> 6, lane = threadIdx.x & 63;
    const int t = blockIdx.x * 4 + wave;             // grid = BT/4
    float m[4], l[4];
#pragma unroll
    for (int c = 0; c < 4; c++) {
        const int j = c * 64 + lane;
        const bool ok = j < NVT;
        m[c] = ok ? part_m[(size_t)t * PJ + j] : -1e30f;
        l[c] = ok ? part_l[(size_t)t * PJ + j] : 0.f;
    }
    float M = fmaxf(fmaxf(m[0], m[1]), fmaxf(m[2], m[3]));
#pragma unroll
    for (int d = 1; d < 64; d <<= 1) M = fmaxf(M, __shfl_xor(M, d));
    float S = l[0] * __expf(m[0] - M) + l[1] * __expf(m[1] - M) +
              l[2] * __expf(m[2] - M) + l[3] * __expf(m[3] - M);
#pragma unroll
    for (int d = 1; d < 64; d <<= 1) S += __shfl_xor(S, d);

    __shared__ float sm[4], sc[4];
    if (lane == 0) {
        const int tg = target[t];
        float loss = 0.f, cnt = 0.f;
        if (tg != -100) {
            loss = (M + __logf(S)) - tgt_logit[t];
            cnt  = 1.f;
        }
        sm[wave] = loss; sc[wave] = cnt;
    }
    __syncthreads();
    if (threadIdx.x == 0) {
        float Ls = sm[0] + sm[1] + sm[2] + sm[3];
        float Cs = sc[0] + sc[1] + sc[2] + sc[3];
        atomicAdd(&accum[0], Ls);
        atomicAdd(&accum[1], Cs);
    }
}

__global__ void final_div(const float* __restrict__ accum, float* __restrict__ out) {
    out[0] = accum[0] / fmaxf(accum[1], 1.f);
}

extern "C" void kernel_launch(void* const* d_in, const int* in_sizes, int n_in,
                              void* d_out, int out_size, void* d_ws, size_t ws_size,
                              hipStream_t stream) {
    const float* x      = (const float*)d_in[0];
    const int*   target = (const int*)d_in[1];
    const float* w      = (const float*)d_in[2];
    const float* bias   = (const float*)d_in[3];

    char* ws = (char*)d_ws;
    size_t off = 0;
    auto alloc = [&](size_t bytes) {
        void* p = ws + off;
        off += (bytes + 255) & ~(size_t)255;
        return p;
    };
    uint8_t* Xq   = (uint8_t*)alloc((size_t)BT * H);
    uint8_t* Wq   = (uint8_t*)alloc((size_t)V * H);
    float* part_m = (float*)alloc((size_t)BT * PJ * 4);
    float* part_l = (float*)alloc((size_t)BT * PJ * 4);
    float* tgtl   = (float*)alloc((size_t)BT * 4);
    float* accum  = (float*)alloc(256);

    const int nq = BT * H / 4 + (int)((size_t)V * H / 4);
    quant_all<<<(nq + 255) / 256, 256, 0, stream>>>(
        (const float4*)x, (const float4*)w, (int*)Xq, (int*)Wq, accum);

    dim3 grid(NRT, NVT);  // x fastest: consecutive blocks share the same W-tile
    gemm_lse<<<grid, 256, 0, stream>>>(Xq, Wq, bias, target, part_m, part_l, tgtl);

    finalize<<<BT / 4, 256, 0, stream>>>(part_m, part_l, tgtl, target, accum);
    final_div<<<1, 1, 0, stream>>>(accum, (float*)d_out);
}

// Round 4
// 712.386 us; speedup vs baseline: 1.5000x; 1.1247x over previous
//
#include <hip/hip_runtime.h>
#include <hip/hip_bf16.h>
#include <cstdint>

#define BT 4096
#define H  2048
#define V  32000
#define TM 128
#define TN 128
#define BK 128          // fp8 bytes == elements
#define NVT (V/TN)      // 250
#define NRT (BT/TM)     // 32
#define PJ  256         // padded partials row stride (floats)
#define WSCALE 64.0f
#define INV_WSCALE 0.015625f

typedef int   v8i   __attribute__((ext_vector_type(8)));
typedef float f32x4 __attribute__((ext_vector_type(4)));

__device__ __forceinline__ void async_load16(const void* g, void* l) {
    __builtin_amdgcn_global_load_lds(
        (__attribute__((address_space(1))) uint32_t*)(void*)g,
        (__attribute__((address_space(3))) uint32_t*)l, 16, 0, 0);
}

// ------- quantize X and W fp32 -> fp8 e4m3 in ONE kernel, 16B/lane loads ----
__global__ void quant_all(const float4* __restrict__ X4, const float4* __restrict__ W4,
                          int* __restrict__ Xq, int* __restrict__ Wq,
                          float* __restrict__ accum) {
    const int NX = BT * H / 4;
    const int NW = (int)((size_t)V * H / 4);
    int i = blockIdx.x * blockDim.x + threadIdx.x;
    if (i == 0) { accum[0] = 0.f; accum[1] = 0.f; }
    if (i < NX) {
        float4 v = X4[i];
        int p = __builtin_amdgcn_cvt_pk_fp8_f32(v.x, v.y, 0, false);
        p     = __builtin_amdgcn_cvt_pk_fp8_f32(v.z, v.w, p, true);
        Xq[i] = p;
    } else if (i < NX + NW) {
        int j = i - NX;
        float4 v = W4[j];
        int p = __builtin_amdgcn_cvt_pk_fp8_f32(v.x * WSCALE, v.y * WSCALE, 0, false);
        p     = __builtin_amdgcn_cvt_pk_fp8_f32(v.z * WSCALE, v.w * WSCALE, p, true);
        Wq[j] = p;
    }
}

// ---------------- fused fp8 GEMM tile + online LSE partials ----------------
// logits[t,v] = (sum_h xq[t,h]*(64*w)q[v,h]) / 64 + bias[v]
// MX-scaled MFMA with all-ones E8M0 scales == pure fp8 GEMM at 2x bf16 rate.
// __launch_bounds__(256,3): cap per-wave regs to ~170 so 3 blocks/CU fit
// (R3 measured 112 VGPR + 64 acc = 176 -> only 2 blocks/CU, 22% occupancy).
__global__ __launch_bounds__(256, 3) void gemm_lse(
    const uint8_t* __restrict__ Xq,          // [BT,H] fp8
    const uint8_t* __restrict__ Wq,          // [V,H]  fp8 (pre-scaled x64)
    const float* __restrict__ bias,          // [V]
    const int*  __restrict__ target,         // [BT]
    float* __restrict__ part_m,              // [BT][PJ]
    float* __restrict__ part_l,              // [BT][PJ]
    float* __restrict__ tgt_logit)           // [BT]
{
    // XOR-swizzled tiles: physical 16B chunk c of row r holds logical chunk
    // c ^ (r&7) (swizzle on the GLOBAL side; global_load_lds LDS side is fixed).
    __shared__ __align__(16) uint8_t As[TM * BK];
    __shared__ __align__(16) uint8_t Bs[TN * BK];
    __shared__ float red_m[2][TM];
    __shared__ float red_l[2][TM];
    __shared__ int   tgts[TM];

    const int tid  = threadIdx.x;
    const int lane = tid & 63;
    const int wave = tid >> 6;
    const int wm   = wave >> 1;      // 64-row half
    const int wn   = wave & 1;       // 64-col half
    const int row0 = blockIdx.x * TM;
    const int col0 = blockIdx.y * TN;

    if (tid < TM) tgts[tid] = target[row0 + tid];

    f32x4 acc[4][4];
#pragma unroll
    for (int i = 0; i < 4; i++)
#pragma unroll
        for (int j = 0; j < 4; j++) acc[i][j] = (f32x4){0.f, 0.f, 0.f, 0.f};

    // staging: lane l -> row 8g+l/8, physical chunk l%8 holds logical (l%8)^(l/8)
    const int srow   = lane >> 3;                    // 0..7
    const int schunk = ((lane & 7) ^ srow) * 16;     // swizzled byte offset

    // two incremented pointers instead of per-iter address math (reg pressure)
    const uint8_t* Aptr = Xq + (size_t)row0 * H + (size_t)(wave * 32 + srow) * H + schunk;
    const uint8_t* Bptr = Wq + (size_t)col0 * H + (size_t)(wave * 32 + srow) * H + schunk;

    const int lr  = lane & 15;
    const int g32 = lane >> 4;       // k-group: logical chunks {2g,2g+1}

    for (int k0 = 0; k0 < H; k0 += BK) {
#pragma unroll
        for (int L = 0; L < 4; L++) {
            const int g = wave * 4 + L;              // rows 8g..8g+7
            async_load16(Aptr + (size_t)(8 * L) * H, &As[g * 1024]);
            async_load16(Bptr + (size_t)(8 * L) * H, &Bs[g * 1024]);
        }
        Aptr += BK;
        Bptr += BK;
        __syncthreads();

        union Frag { int4 q[2]; v8i v; };
        Frag af[4], bf[4];
#pragma unroll
        for (int i = 0; i < 4; i++) {
            const int r  = wm * 64 + i * 16 + lr;
            const int p0 = (2 * g32) ^ (r & 7);
            const int4* base = (const int4*)&As[r * BK];
            af[i].q[0] = base[p0];
            af[i].q[1] = base[p0 ^ 1];
        }
#pragma unroll
        for (int j = 0; j < 4; j++) {
            const int r  = wn * 64 + j * 16 + lr;
            const int p0 = (2 * g32) ^ (r & 7);
            const int4* base = (const int4*)&Bs[r * BK];
            bf[j].q[0] = base[p0];
            bf[j].q[1] = base[p0 ^ 1];
        }
#pragma unroll
        for (int i = 0; i < 4; i++)
#pragma unroll
            for (int j = 0; j < 4; j++)
                acc[i][j] = __builtin_amdgcn_mfma_scale_f32_16x16x128_f8f6f4(
                    af[i].v, bf[j].v, acc[i][j],
                    0 /*A=e4m3*/, 0 /*B=e4m3*/,
                    0, 0x7f7f7f7f, 0, 0x7f7f7f7f);   // all scales = 2^0
        __syncthreads();
    }

    // ---- epilogue: unscale, bias, target grab, max-first reduce, ONE exp pass
    const int quad = lane >> 4;
    float bj[4];
#pragma unroll
    for (int j = 0; j < 4; j++) bj[j] = bias[col0 + wn * 64 + j * 16 + lr];

#pragma unroll
    for (int i = 0; i < 4; i++) {
#pragma unroll
        for (int r = 0; r < 4; r++) {
            const int rit = wm * 64 + i * 16 + quad * 4 + r;  // C/D: row=quad*4+reg
            float v[4];
#pragma unroll
            for (int j = 0; j < 4; j++) v[j] = acc[i][j][r] * INV_WSCALE + bj[j];
            const int tg = tgts[rit];
#pragma unroll
            for (int j = 0; j < 4; j++)
                if (col0 + wn * 64 + j * 16 + lr == tg)
                    tgt_logit[row0 + rit] = v[j];  // exactly one writer globally
            // max over this row's 64 cols (4 regs x 16 lanes), cheap fmax shuffles
            float mx = fmaxf(fmaxf(v[0], v[1]), fmaxf(v[2], v[3]));
#pragma unroll
            for (int d = 1; d < 16; d <<= 1) mx = fmaxf(mx, __shfl_xor(mx, d));
            // single exp pass, then sum shuffles
            float se = __expf(v[0] - mx) + __expf(v[1] - mx) +
                       __expf(v[2] - mx) + __expf(v[3] - mx);
#pragma unroll
            for (int d = 1; d < 16; d <<= 1) se += __shfl_xor(se, d);
            if (lr == 0) { red_m[wn][rit] = mx; red_l[wn][rit] = se; }
        }
    }
    __syncthreads();
    if (tid < TM) {
        float m0 = red_m[0][tid], m1 = red_m[1][tid];
        float l0 = red_l[0][tid], l1 = red_l[1][tid];
        float M = fmaxf(m0, m1);
        float L = l0 * __expf(m0 - M) + l1 * __expf(m1 - M);
        // transposed layout: one contiguous row of 250 partials per token
        part_m[(size_t)(row0 + tid) * PJ + blockIdx.y] = M;
        part_l[(size_t)(row0 + tid) * PJ + blockIdx.y] = L;
    }
}

// ------- merge partials: one WAVE per token, lane-parallel over V-tiles -----
__global__ void finalize(const float* __restrict__ part_m,
                         const float* __restrict__ part_l,
                         const float* __restrict__ tgt_logit,
                         const int*  __restrict__ target,
                         float* __restrict__ accum)  // accum[0]=sum, accum[1]=count
{
    const int wave = threadIdx.x >> 6, lane = threadIdx.x & 63;
    const int t = blockIdx.x * 4 + wave;             // grid = BT/4
    float m[4], l[4];
#pragma unroll
    for (int c = 0; c < 4; c++) {
        const int j = c * 64 + lane;
        const bool ok = j < NVT;
        m[c] = ok ? part_m[(size_t)t * PJ + j] : -1e30f;
        l[c] = ok ? part_l[(size_t)t * PJ + j] : 0.f;
    }
    float M = fmaxf(fmaxf(m[0], m[1]), fmaxf(m[2], m[3]));
#pragma unroll
    for (int d = 1; d < 64; d <<= 1) M = fmaxf(M, __shfl_xor(M, d));
    float S = l[0] * __expf(m[0] - M) + l[1] * __expf(m[1] - M) +
              l[2] * __expf(m[2] - M) + l[3] * __expf(m[3] - M);
#pragma unroll
    for (int d = 1; d < 64; d <<= 1) S += __shfl_xor(S, d);

    __shared__ float sm[4], sc[4];
    if (lane == 0) {
        const int tg = target[t];
        float loss = 0.f, cnt = 0.f;
        if (tg != -100) {
            loss = (M + __logf(S)) - tgt_logit[t];
            cnt  = 1.f;
        }
        sm[wave] = loss; sc[wave] = cnt;
    }
    __syncthreads();
    if (threadIdx.x == 0) {
        float Ls = sm[0] + sm[1] + sm[2] + sm[3];
        float Cs = sc[0] + sc[1] + sc[2] + sc[3];
        atomicAdd(&accum[0], Ls);
        atomicAdd(&accum[1], Cs);
    }
}

__global__ void final_div(const float* __restrict__ accum, float* __restrict__ out) {
    out[0] = accum[0] / fmaxf(accum[1], 1.f);
}

extern "C" void kernel_launch(void* const* d_in, const int* in_sizes, int n_in,
                              void* d_out, int out_size, void* d_ws, size_t ws_size,
                              hipStream_t stream) {
    const float* x      = (const float*)d_in[0];
    const int*   target = (const int*)d_in[1];
    const float* w      = (const float*)d_in[2];
    const float* bias   = (const float*)d_in[3];

    char* ws = (char*)d_ws;
    size_t off = 0;
    auto alloc = [&](size_t bytes) {
        void* p = ws + off;
        off += (bytes + 255) & ~(size_t)255;
        return p;
    };
    uint8_t* Xq   = (uint8_t*)alloc((size_t)BT * H);
    uint8_t* Wq   = (uint8_t*)alloc((size_t)V * H);
    float* part_m = (float*)alloc((size_t)BT * PJ * 4);
    float* part_l = (float*)alloc((size_t)BT * PJ * 4);
    float* tgtl   = (float*)alloc((size_t)BT * 4);
    float* accum  = (float*)alloc(256);

    const int nq = BT * H / 4 + (int)((size_t)V * H / 4);
    quant_all<<<(nq + 255) / 256, 256, 0, stream>>>(
        (const float4*)x, (const float4*)w, (int*)Xq, (int*)Wq, accum);

    dim3 grid(NRT, NVT);  // x fastest: consecutive blocks share the same W-tile
    gemm_lse<<<grid, 256, 0, stream>>>(Xq, Wq, bias, target, part_m, part_l, tgtl);

    finalize<<<BT / 4, 256, 0, stream>>>(part_m, part_l, tgtl, target, accum);
    final_div<<<1, 1, 0, stream>>>(accum, (float*)d_out);
}